// Round 11
// baseline (1140.654 us; speedup 1.0000x reference)
//
#include <hip/hip_runtime.h>
#include <math.h>

#define HW     16384
#define WIDTH  128
#define CDIM   384
#define QKVC   1152
#define HEADS  8
#define CH     48
#define NSPLIT 32
#define GK     384

typedef unsigned short u16;
typedef short bf16x8 __attribute__((ext_vector_type(8)));
typedef u16 u16x8 __attribute__((ext_vector_type(8)));
typedef float f32x4 __attribute__((ext_vector_type(4)));

// ---- fp32 -> bf16 hi/lo split (RNE both) ----
__device__ __forceinline__ void split2(float x, u16& h, u16& l) {
    union { float f; unsigned u; } a, b, c;
    a.f = x;
    unsigned hu = (a.u + 0x7fffu + ((a.u >> 16) & 1u)) & 0xffff0000u;
    b.u = hu;
    h = (u16)(hu >> 16);
    c.f = x - b.f;
    l = (u16)((c.u + 0x7fffu + ((c.u >> 16) & 1u)) >> 16);
}

__device__ __forceinline__ void gload16(const void* g, void* l) {
    __builtin_amdgcn_global_load_lds((const __attribute__((address_space(1))) unsigned int*)g,
                                     (__attribute__((address_space(3))) unsigned int*)l, 16, 0, 0);
}

// ---------------- MFMA split-bf16 GEMM: BM=128 BN=128 BK=32, 4 waves ----------------
// A (small, L2-hot) is loaded per-K-step straight into registers — issued BEFORE the
// B-tile STAGE so the compiler's vmcnt wait for A leaves the B prefetch in flight.
// Only B is LDS double-buffered (2 x 16KB = 32KB) -> 4 blocks/CU; the drain stall of
// one block is hidden by the other three. Race-free: all cross-wave sync is
// __syncthreads() (r9 post-mortem: counted-vmcnt raw-barrier pipeline retired).
__global__ __launch_bounds__(256, 4)
void mfma_gemm(const u16* __restrict__ Ah, const u16* __restrict__ Al,
               const u16* __restrict__ Bh, const u16* __restrict__ Bl,
               float* __restrict__ C, int nmb,
               long abs_, long bbs, long cbs)
{
    __shared__ char smem[32768];
    const int tot = gridDim.x * gridDim.y;
    const int per = tot >> 3;
    const int fl  = blockIdx.x + gridDim.x * blockIdx.y;
    const int f2  = (fl & 7) * per + (fl >> 3);
    const int nblk = f2 / nmb, mblk = f2 % nmb;
    const int b = blockIdx.z;
    Ah += (long)b * abs_; Al += (long)b * abs_;
    Bh += (long)b * bbs;  Bl += (long)b * bbs;
    C  += (long)b * cbs;
    const int m0 = mblk * 128, n0 = nblk * 128;

    const int tid  = threadIdx.x;
    const int wave = tid >> 6, lane = tid & 63;
    const int lr = lane & 15, lg = lane >> 4;
    const int wm = wave >> 1, wn = wave & 1;     // 2x2 wave grid, wave tile 64x64

    const int srow = tid >> 2;                   // 0..63
    const int kc   = tid & 3;
    const int sw   = kc ^ ((srow >> 1) & 3);

    f32x4 acc[4][4];
#pragma unroll
    for (int i = 0; i < 4; ++i)
#pragma unroll
        for (int j = 0; j < 4; ++j) acc[i][j] = (f32x4){0.f, 0.f, 0.f, 0.f};

    // B-only staging: Bh rows0-63 @0, rows64-127 @4096; Bl @8192/12288 per 16KB buffer
#define STAGEB(bs, kt) do { char* LL = smem + (bs) * 16384;                         \
        const long ko = (long)(kt) * 32 + sw * 8;                                   \
        gload16(Bh + (long)(n0 + srow) * GK      + ko, LL + tid * 16);              \
        gload16(Bh + (long)(n0 + 64 + srow) * GK + ko, LL + 4096  + tid * 16);      \
        gload16(Bl + (long)(n0 + srow) * GK      + ko, LL + 8192  + tid * 16);      \
        gload16(Bl + (long)(n0 + 64 + srow) * GK + ko, LL + 12288 + tid * 16);      \
    } while (0)

    STAGEB(0, 0);
    __syncthreads();                             // tile 0 landed (full drain)
#pragma unroll
    for (int kt = 0; kt < 12; ++kt) {            // GK/32 == 12
        // A fragments: registers, direct from L2. Issued FIRST (oldest in vmcnt
        // order) so waiting on them does not drain the B-stage loads below.
        bf16x8 af[4][2];
#pragma unroll
        for (int mi = 0; mi < 4; ++mi) {
            long r = m0 + wm * 64 + mi * 16 + lr;
            af[mi][0] = *(const bf16x8*)(Ah + r * GK + kt * 32 + lg * 8);
            af[mi][1] = *(const bf16x8*)(Al + r * GK + kt * 32 + lg * 8);
        }
        if (kt + 1 < 12) STAGEB((kt + 1) & 1, kt + 1);   // prefetch next B tile

        const char* L = smem + (kt & 1) * 16384;
        bf16x8 bf[4][2];
#pragma unroll
        for (int ni = 0; ni < 4; ++ni) {
            int r = wn * 64 + ni * 16 + lr;
            int off = r * 64 + (((lg ^ (r >> 1)) & 3) << 4);
            bf[ni][0] = *(const bf16x8*)(L + off);
            bf[ni][1] = *(const bf16x8*)(L + 8192 + off);
        }

        __builtin_amdgcn_s_setprio(1);
#pragma unroll
        for (int mi = 0; mi < 4; ++mi)
#pragma unroll
            for (int ni = 0; ni < 4; ++ni) {
                acc[mi][ni] = __builtin_amdgcn_mfma_f32_16x16x32_bf16(af[mi][0], bf[ni][0], acc[mi][ni], 0, 0, 0);
                acc[mi][ni] = __builtin_amdgcn_mfma_f32_16x16x32_bf16(af[mi][0], bf[ni][1], acc[mi][ni], 0, 0, 0);
                acc[mi][ni] = __builtin_amdgcn_mfma_f32_16x16x32_bf16(af[mi][1], bf[ni][0], acc[mi][ni], 0, 0, 0);
            }
        __builtin_amdgcn_s_setprio(0);
        __syncthreads();   // drains vmcnt (next B tile in LDS) + all waves done reading cur
    }
#undef STAGEB

#pragma unroll
    for (int mi = 0; mi < 4; ++mi)
#pragma unroll
        for (int ni = 0; ni < 4; ++ni) {
            int row = m0 + wm * 64 + mi * 16 + lg * 4;
            int col = n0 + wn * 64 + ni * 16 + lr;
            float* cp = C + (long)row * HW + col;
            cp[0]          = acc[mi][ni][0];
            cp[(long)HW]   = acc[mi][ni][1];
            cp[2L * HW]    = acc[mi][ni][2];
            cp[3L * HW]    = acc[mi][ni][3];
        }
}

// ---------------- transpose + split convert: [384][HW] fp32 -> [HW][384] bf16 hi/lo ----
__global__ __launch_bounds__(256)
void convT_kernel(const float* __restrict__ in, u16* __restrict__ oh, u16* __restrict__ ol,
                  long ibs, long obs)
{
    const int b = blockIdx.z;
    in += (long)b * ibs; oh += (long)b * obs; ol += (long)b * obs;
    __shared__ float t[32][33];
    const int p0 = blockIdx.x * 32, c0 = blockIdx.y * 32;
    const int ty = threadIdx.x >> 5, tx = threadIdx.x & 31;
#pragma unroll
    for (int it = 0; it < 4; ++it) {
        int c = ty + it * 8;
        t[c][tx] = in[(long)(c0 + c) * HW + p0 + tx];
    }
    __syncthreads();
    const int cp = threadIdx.x & 15;
    const int py = threadIdx.x >> 4;
#pragma unroll
    for (int half = 0; half < 2; ++half) {
        int p = py + half * 16;
        u16 h0, l0, h1, l1;
        split2(t[2 * cp][p], h0, l0);
        split2(t[2 * cp + 1][p], h1, l1);
        long o = (long)(p0 + p) * CDIM + c0 + 2 * cp;
        *(ushort2*)&oh[o] = (ushort2){h0, h1};
        *(ushort2*)&ol[o] = (ushort2){l0, l1};
    }
}

// ---------------- elementwise split convert (qkv_w) ----------------
__global__ __launch_bounds__(256)
void convA_kernel(const float* __restrict__ in, u16* __restrict__ oh, u16* __restrict__ ol, int n)
{
    int i = blockIdx.x * 256 + threadIdx.x;
    if (i < n) split2(in[i], oh[i], ol[i]);
}

// ---------------- depthwise 3x3, pad 1 — q,k channels only (0..767) ----------------
__global__ __launch_bounds__(256)
void dwconv_kernel(const float* __restrict__ in, const float* __restrict__ w,
                   float* __restrict__ out)
{
    const long base = (long)blockIdx.y * QKVC * HW;
    const int idx = blockIdx.x * 256 + threadIdx.x;      // over 768*HW/8
    const int ch = idx >> 11;
    const int wi = idx & 2047;
    const int y = wi >> 4, x0 = (wi & 15) * 8;
    const float* wp = w + ch * 9;
    const float* ip = in + base + (long)ch * HW;
    float o[8] = {0.f, 0.f, 0.f, 0.f, 0.f, 0.f, 0.f, 0.f};
#pragma unroll
    for (int dy = -1; dy <= 1; ++dy) {
        int yy = y + dy;
        if ((unsigned)yy >= 128u) continue;
        const float* rp = ip + yy * WIDTH + x0;
        float4 a  = *(const float4*)rp;
        float4 bq = *(const float4*)(rp + 4);
        float v[10] = { (x0 > 0) ? rp[-1] : 0.f,
                        a.x, a.y, a.z, a.w, bq.x, bq.y, bq.z, bq.w,
                        (x0 < 120) ? rp[8] : 0.f };
        float w0 = wp[(dy + 1) * 3], w1 = wp[(dy + 1) * 3 + 1], w2 = wp[(dy + 1) * 3 + 2];
#pragma unroll
        for (int j = 0; j < 8; ++j)
            o[j] = fmaf(w0, v[j], fmaf(w1, v[j + 1], fmaf(w2, v[j + 2], o[j])));
    }
    float* op = out + base + (long)ch * HW + y * WIDTH + x0;
    *(float4*)op       = (float4){o[0], o[1], o[2], o[3]};
    *(float4*)(op + 4) = (float4){o[4], o[5], o[6], o[7]};
}

// ---------------- depthwise 3x3 for v + fused transpose/split to vt[HW][384] ----------
__global__ __launch_bounds__(256)
void dwconv_vT_kernel(const float* __restrict__ in, const float* __restrict__ w,
                      u16* __restrict__ oh, u16* __restrict__ ol, long ibs, long obs)
{
    const int b  = blockIdx.z;
    const int cg = blockIdx.y;                   // channel group (96 ch)
    const int p0 = blockIdx.x * 64;
    const int y  = p0 >> 7, xh = p0 & 127;
    __shared__ unsigned pk[64][97];

    const int tid = threadIdx.x;
    const int seg = tid & 7;
    const int chl = tid >> 3;
    const int x0  = xh + seg * 8;
#pragma unroll
    for (int cp = 0; cp < 3; ++cp) {
        const int cl = cp * 32 + chl;
        const int c  = cg * 96 + cl;
        const float* ip = in + (long)b * ibs + (long)(768 + c) * HW;
        const float* wp = w + (768 + c) * 9;
        float o[8] = {0.f, 0.f, 0.f, 0.f, 0.f, 0.f, 0.f, 0.f};
#pragma unroll
        for (int dy = -1; dy <= 1; ++dy) {
            int yy = y + dy;
            if ((unsigned)yy >= 128u) continue;
            const float* rp = ip + yy * WIDTH + x0;
            float4 a  = *(const float4*)rp;
            float4 bq = *(const float4*)(rp + 4);
            float v[10] = { (x0 > 0) ? rp[-1] : 0.f,
                            a.x, a.y, a.z, a.w, bq.x, bq.y, bq.z, bq.w,
                            (x0 < 120) ? rp[8] : 0.f };
            float w0 = wp[(dy + 1) * 3], w1 = wp[(dy + 1) * 3 + 1], w2 = wp[(dy + 1) * 3 + 2];
#pragma unroll
            for (int j = 0; j < 8; ++j)
                o[j] = fmaf(w0, v[j], fmaf(w1, v[j + 1], fmaf(w2, v[j + 2], o[j])));
        }
#pragma unroll
        for (int j = 0; j < 8; ++j) {
            u16 hh, ll;
            split2(o[j], hh, ll);
            pk[seg * 8 + j][cl] = ((unsigned)hh << 16) | ll;
        }
    }
    __syncthreads();
    const int px = tid >> 2, qt = tid & 3;
    u16 hs[24], ls[24];
#pragma unroll
    for (int j = 0; j < 24; ++j) {
        unsigned v = pk[px][qt * 24 + j];
        hs[j] = (u16)(v >> 16);
        ls[j] = (u16)(v & 0xffffu);
    }
    u16* ph = oh + (long)b * obs + (long)(p0 + px) * CDIM + cg * 96 + qt * 24;
    u16* pl = ol + (long)b * obs + (long)(p0 + px) * CDIM + cg * 96 + qt * 24;
#pragma unroll
    for (int j = 0; j < 3; ++j) {
        *(u16x8*)(ph + j * 8) = *(const u16x8*)&hs[j * 8];
        *(u16x8*)(pl + j * 8) = *(const u16x8*)&ls[j * 8];
    }
}

// ---------------- attn partial: 48x48 dots over 512-px slice + q/k sumsq partials ----
// LDS transposed to c-major qs[48][68]: staging writes AND compute reads are float4
// (b128), ~2x fewer LDS issue cycles than the n-major b32 layout. fma order stays
// n-ascending per accumulator -> bitwise-identical results.
__global__ __launch_bounds__(256)
void attn_partial_kernel(const float* __restrict__ dw, float* __restrict__ part,
                         float* __restrict__ part2, long ps, long p2s)
{
    const int split = blockIdx.x, h = blockIdx.y, b = blockIdx.z;
    const int n0 = split * (HW / NSPLIT);
    const float* qbase = dw + ((long)b * QKVC + h * CH) * HW;
    const float* kbase = dw + ((long)b * QKVC + CDIM + h * CH) * HW;
    __shared__ float qs[48][68];
    __shared__ float ks[48][68];
    const int tid = threadIdx.x;
    const int tr = tid >> 4, tc = tid & 15;
    const int c0 = tr * 3, d0 = tc * 3;
    float acc[3][3] = {{0.f}};
    float qss[3] = {0.f, 0.f, 0.f}, kss[3] = {0.f, 0.f, 0.f};
    const int cA = tid >> 4;
    const int nq = (tid & 15) * 4;

#define DOT4(I, J, Q, K) do {                               \
        acc[I][J] = fmaf((Q).x, (K).x, acc[I][J]);          \
        acc[I][J] = fmaf((Q).y, (K).y, acc[I][J]);          \
        acc[I][J] = fmaf((Q).z, (K).z, acc[I][J]);          \
        acc[I][J] = fmaf((Q).w, (K).w, acc[I][J]);          \
    } while (0)

    for (int ns = 0; ns < HW / NSPLIT; ns += 64) {
        __syncthreads();
#pragma unroll
        for (int t = 0; t < 3; ++t) {
            int c = cA + t * 16;
            float4 qv = *(const float4*)(qbase + (long)c * HW + n0 + ns + nq);
            float4 kv = *(const float4*)(kbase + (long)c * HW + n0 + ns + nq);
            *(float4*)&qs[c][nq] = qv;
            *(float4*)&ks[c][nq] = kv;
            qss[t] += qv.x * qv.x + qv.y * qv.y + qv.z * qv.z + qv.w * qv.w;
            kss[t] += kv.x * kv.x + kv.y * kv.y + kv.z * kv.z + kv.w * kv.w;
        }
        __syncthreads();
#pragma unroll 4
        for (int nn = 0; nn < 64; nn += 4) {
            float4 qa = *(const float4*)&qs[c0 + 0][nn];
            float4 qb = *(const float4*)&qs[c0 + 1][nn];
            float4 qc = *(const float4*)&qs[c0 + 2][nn];
            float4 ka = *(const float4*)&ks[d0 + 0][nn];
            float4 kb = *(const float4*)&ks[d0 + 1][nn];
            float4 kc = *(const float4*)&ks[d0 + 2][nn];
            DOT4(0, 0, qa, ka); DOT4(0, 1, qa, kb); DOT4(0, 2, qa, kc);
            DOT4(1, 0, qb, ka); DOT4(1, 1, qb, kb); DOT4(1, 2, qb, kc);
            DOT4(2, 0, qc, ka); DOT4(2, 1, qc, kb); DOT4(2, 2, qc, kc);
        }
    }
#undef DOT4
#pragma unroll
    for (int m = 1; m < 16; m <<= 1) {
#pragma unroll
        for (int t = 0; t < 3; ++t) {
            qss[t] += __shfl_xor(qss[t], m);
            kss[t] += __shfl_xor(kss[t], m);
        }
    }
    if ((tid & 15) == 0) {
        float* p2 = part2 + (long)b * p2s + ((long)h * NSPLIT + split) * 96;
#pragma unroll
        for (int t = 0; t < 3; ++t) {
            p2[cA + t * 16]      = qss[t];
            p2[48 + cA + t * 16] = kss[t];
        }
    }
    float* po = part + (long)b * ps + ((long)h * NSPLIT + split) * (CH * CH);
#pragma unroll
    for (int i = 0; i < 3; ++i)
#pragma unroll
        for (int j = 0; j < 3; ++j)
            po[(c0 + i) * CH + d0 + j] = acc[i][j];
}

// ---------------- attn reduce: sum partials, inv-norms from sumsq, temperature ----
__global__ __launch_bounds__(256)
void attn_reduce_kernel(const float* __restrict__ part, const float* __restrict__ part2,
                        const float* __restrict__ temp, float* __restrict__ attn,
                        long ps, long p2s, long as_)
{
    const int seg = blockIdx.x, h = blockIdx.y, b = blockIdx.z;
    const float* pp = part + (long)b * ps + (long)h * NSPLIT * (CH * CH);
    const float* p2 = part2 + (long)b * p2s + (long)h * NSPLIT * 96;
    __shared__ float sinv[96];
    if (threadIdx.x < 96) {
        float s = 0.f;
        for (int sp = 0; sp < NSPLIT; ++sp) s += p2[sp * 96 + threadIdx.x];
        sinv[threadIdx.x] = 1.f / fmaxf(sqrtf(s), 1e-12f);
    }
    __syncthreads();
    const float t = temp[h];
    const int idx = seg * 256 + threadIdx.x;
    const int c = idx / CH, d = idx % CH;
    float s = 0.f;
    for (int sp = 0; sp < NSPLIT; ++sp) s += pp[sp * (CH * CH) + idx];
    attn[(long)b * as_ + (long)h * (CH * CH) + idx] = s * sinv[c] * sinv[48 + d] * t;
}

// ---------------- two-stage masked softmax -> combined weights W ----------------
__global__ __launch_bounds__(256)
void maskw_kernel(const float* __restrict__ attn, const float* __restrict__ attns,
                  float* __restrict__ W, long as_, long ws_)
{
    const int h = blockIdx.y, b = blockIdx.z;
    const int wave = threadIdx.x >> 6, lane = threadIdx.x & 63;
    const int r = blockIdx.x * 4 + wave;                 // 0..47
    const float* ap = attn + (long)b * as_ + (long)h * (CH * CH) + (long)r * CH;
    float a = (lane < CH) ? ap[lane] : -3.4e38f;

    int rank = 0;
#pragma unroll
    for (int j = 0; j < CH; ++j) {
        float aj = __shfl(a, j);
        rank += (aj > a) || (aj == a && j < lane);
    }
    const bool keep = (lane < CH) && (rank < 24);
    float m = keep ? a : -3.4e38f;
#pragma unroll
    for (int o = 32; o > 0; o >>= 1) m = fmaxf(m, __shfl_xor(m, o));
    float e = keep ? expf(a - m) : 0.f;
    float s = e;
#pragma unroll
    for (int o = 32; o > 0; o >>= 1) s += __shfl_xor(s, o);
    const float A1 = e / s;

    int rank2 = 0;
#pragma unroll
    for (int j = 0; j < CH; ++j) {
        float aj = __shfl(A1, j);
        rank2 += (aj > A1) || (aj == A1 && j < lane);
    }
    const bool keep2 = (lane < CH) && (rank2 < 36);
    float m2 = keep2 ? A1 : -3.4e38f;
#pragma unroll
    for (int o = 32; o > 0; o >>= 1) m2 = fmaxf(m2, __shfl_xor(m2, o));
    float e2 = keep2 ? expf(A1 - m2) : 0.f;
    float s2 = e2;
#pragma unroll
    for (int o = 32; o > 0; o >>= 1) s2 += __shfl_xor(s2, o);

    if (lane < CH)
        W[(long)b * ws_ + (long)h * (CH * CH) + (long)r * CH + lane] =
            attns[0] * A1 + attns[1] * (e2 / s2);
}

// ---------------- M = P @ blockdiag(W), written as bf16 hi/lo planes ----------------
__global__ __launch_bounds__(256)
void mbuild_kernel(const float* __restrict__ P, const float* __restrict__ W,
                   u16* __restrict__ Mh, u16* __restrict__ Ml, long ws_, long ms)
{
    const int b = blockIdx.y;
    const int idx = blockIdx.x * 256 + threadIdx.x;
    const int o = idx / CDIM, col = idx % CDIM;
    const int h = col / CH, d = col % CH;
    const float* wp = W + (long)b * ws_ + (long)h * (CH * CH) + d;
    const float* pp = P + (long)o * CDIM + h * CH;
    float s = 0.f;
#pragma unroll
    for (int c = 0; c < CH; ++c) s = fmaf(pp[c], wp[c * CH], s);
    u16 hh, ll;
    split2(s, hh, ll);
    Mh[(long)b * ms + idx] = hh;
    Ml[(long)b * ms + idx] = ll;
}

extern "C" void kernel_launch(void* const* d_in, const int* in_sizes, int n_in,
                              void* d_out, int out_size, void* d_ws, size_t ws_size,
                              hipStream_t stream)
{
    const float* x      = (const float*)d_in[0];
    const float* qkv_w  = (const float*)d_in[1];
    const float* dw_w   = (const float*)d_in[2];
    const float* proj_w = (const float*)d_in[3];
    const float* temp   = (const float*)d_in[4];
    const float* attns  = (const float*)d_in[5];
    float* out = (float*)d_out;

    const size_t perbB = (size_t)QKVC * HW * 4;
    auto need = [&](int nb) -> size_t {
        return (size_t)nb * 2 * perbB + 4u * QKVC * CDIM + 4096;
    };
    int NB = 4;
    while (NB > 1 && need(NB) > ws_size) NB >>= 1;

    const long fstride = (long)(perbB / 4);   // batch stride in floats
    const long ustride = (long)(perbB / 2);   // batch stride in u16

    const size_t PART_B  = 27u << 20;
    const size_t PART2_B = (29u << 20) + (512u << 10);
    const size_t ATT_B   = 30u << 20;
    const size_t WM_B    = 31u << 20;
    const size_t MH_B    = 32u << 20;
    const size_t ML_B    = 33u << 20;

    char* buf1 = (char*)d_ws;
    char* buf2 = buf1 + (size_t)NB * perbB;
    u16* Ah = (u16*)(buf2 + (size_t)NB * perbB);
    u16* Al = Ah + (size_t)QKVC * CDIM;

    convA_kernel<<<dim3((QKVC * CDIM + 255) / 256), 256, 0, stream>>>(qkv_w, Ah, Al, QKVC * CDIM);

    for (int b0 = 0; b0 < 4; b0 += NB) {
        const int nb = NB;
        float* pre = (float*)buf1;
        float* dwb = (float*)buf2;
        u16* xt_h = (u16*)buf2;                u16* xt_l = xt_h + (size_t)HW * CDIM;
        // vt lives in dwb's (unused) v region: channels 768..1151
        u16* vt_h = (u16*)(dwb + (size_t)768 * HW);
        u16* vt_l = vt_h + (size_t)CDIM * HW;
        float* part  = (float*)(buf1 + PART_B);
        float* part2 = (float*)(buf1 + PART2_B);
        float* attn  = (float*)(buf1 + ATT_B);
        float* Wm    = (float*)(buf1 + WM_B);
        u16* Mh = (u16*)(buf1 + MH_B);
        u16* Ml = (u16*)(buf1 + ML_B);

        // 1) x -> xt (transposed bf16 hi/lo)
        convT_kernel<<<dim3(HW / 32, CDIM / 32, nb), 256, 0, stream>>>(
            x + (size_t)b0 * CDIM * HW, xt_h, xt_l, (long)CDIM * HW, ustride);
        // 2) pre = qkv_w @ x  (MFMA split-bf16, reg-A + B-only LDS, 4 blocks/CU)
        mfma_gemm<<<dim3(HW / 128, QKVC / 128, nb), 256, 0, stream>>>(
            Ah, Al, xt_h, xt_l, pre, QKVC / 128, 0L, ustride, fstride);
        // 3) depthwise 3x3 for q,k (overwrites xt region with dwb)
        dwconv_kernel<<<dim3(768 * HW / 8 / 256, nb), 256, 0, stream>>>(pre, dw_w, dwb);
        // 3b) depthwise 3x3 for v fused with transpose+split -> vt (LDS-transposed, coalesced)
        dwconv_vT_kernel<<<dim3(HW / 64, 4, nb), 256, 0, stream>>>(pre, dw_w, vt_h, vt_l,
                                                                   fstride, ustride);
        // 4) attn partials + sumsq partials (c-major float4 LDS)
        attn_partial_kernel<<<dim3(NSPLIT, HEADS, nb), 256, 0, stream>>>(dwb, part, part2,
                                                                         fstride, fstride);
        // 5) reduce + inv-norms + scale (9-way parallel)
        attn_reduce_kernel<<<dim3(9, HEADS, nb), 256, 0, stream>>>(part, part2, temp, attn,
                                                                   fstride, fstride, fstride);
        // 6) two-stage masked softmax -> W (wave-per-row, shuffle-based)
        maskw_kernel<<<dim3(12, HEADS, nb), 256, 0, stream>>>(attn, attns, Wm, fstride, fstride);
        // 7) M = proj @ blockdiag(W) -> bf16 hi/lo
        mbuild_kernel<<<dim3(CDIM * CDIM / 256, nb), 256, 0, stream>>>(proj_w, Wm, Mh, Ml,
                                                                       fstride, ustride);
        // 8) out = M @ v (MFMA split-bf16)
        mfma_gemm<<<dim3(HW / 128, CDIM / 128, nb), 256, 0, stream>>>(
            Mh, Ml, vt_h, vt_l, out + (size_t)b0 * CDIM * HW, CDIM / 128,
            ustride, ustride, (long)CDIM * HW);
    }
}

// Round 12
// 618.499 us; speedup vs baseline: 1.8442x; 1.8442x over previous
//
#include <hip/hip_runtime.h>
#include <math.h>

#define HW     16384
#define WIDTH  128
#define CDIM   384
#define QKVC   1152
#define HEADS  8
#define CH     48
#define NSPLIT 32
#define GK     384

typedef unsigned short u16;
typedef short bf16x8 __attribute__((ext_vector_type(8)));
typedef u16 u16x8 __attribute__((ext_vector_type(8)));
typedef float f32x4 __attribute__((ext_vector_type(4)));

// ---- fp32 -> bf16 hi/lo split (RNE both) ----
__device__ __forceinline__ void split2(float x, u16& h, u16& l) {
    union { float f; unsigned u; } a, b, c;
    a.f = x;
    unsigned hu = (a.u + 0x7fffu + ((a.u >> 16) & 1u)) & 0xffff0000u;
    b.u = hu;
    h = (u16)(hu >> 16);
    c.f = x - b.f;
    l = (u16)((c.u + 0x7fffu + ((c.u >> 16) & 1u)) >> 16);
}

__device__ __forceinline__ void gload16(const void* g, void* l) {
    __builtin_amdgcn_global_load_lds((const __attribute__((address_space(1))) unsigned int*)g,
                                     (__attribute__((address_space(3))) unsigned int*)l, 16, 0, 0);
}

// ---------------- MFMA split-bf16 GEMM: BM=128 BN=128 BK=32, 4 waves ----------------
// PROVEN CONFIG (r10: 93.5us, MfmaUtil 40%, stable under graph replay).
// 64KB LDS (2 x 32KB dbuf) -> 2 blocks/CU; __syncthreads()-drained 1-deep prefetch.
// r11 post-mortem: reg-A + 4 blocks/CU collapsed L2 reuse (FETCH 56->407MB) — reverted.
// r9 post-mortem: counted-vmcnt raw-barrier pipeline raced under replay — retired.
__global__ __launch_bounds__(256)
void mfma_gemm(const u16* __restrict__ Ah, const u16* __restrict__ Al,
               const u16* __restrict__ Bh, const u16* __restrict__ Bl,
               float* __restrict__ C, int nmb,
               long abs_, long bbs, long cbs)
{
    extern __shared__ char smem[];
    const int tot = gridDim.x * gridDim.y;
    const int per = tot >> 3;
    const int fl  = blockIdx.x + gridDim.x * blockIdx.y;
    const int f2  = (fl & 7) * per + (fl >> 3);
    const int nblk = f2 / nmb, mblk = f2 % nmb;
    const int b = blockIdx.z;
    Ah += (long)b * abs_; Al += (long)b * abs_;
    Bh += (long)b * bbs;  Bl += (long)b * bbs;
    C  += (long)b * cbs;
    const int m0 = mblk * 128, n0 = nblk * 128;

    const int tid  = threadIdx.x;
    const int wave = tid >> 6, lane = tid & 63;
    const int lr = lane & 15, lg = lane >> 4;
    const int wm = wave >> 1, wn = wave & 1;     // 2x2 wave grid, wave tile 64x64

    const int srow = tid >> 2;                   // 0..63
    const int kc   = tid & 3;
    const int sw   = kc ^ ((srow >> 1) & 3);

    f32x4 acc[4][4];
#pragma unroll
    for (int i = 0; i < 4; ++i)
#pragma unroll
        for (int j = 0; j < 4; ++j) acc[i][j] = (f32x4){0.f, 0.f, 0.f, 0.f};

#define STAGE(bs, kt) do { char* LL = smem + (bs) * 32768;                          \
        const long ko = (long)(kt) * 32 + sw * 8;                                   \
        gload16(Ah + (long)(m0 + srow) * GK      + ko, LL + tid * 16);              \
        gload16(Ah + (long)(m0 + 64 + srow) * GK + ko, LL + 4096  + tid * 16);      \
        gload16(Al + (long)(m0 + srow) * GK      + ko, LL + 8192  + tid * 16);      \
        gload16(Al + (long)(m0 + 64 + srow) * GK + ko, LL + 12288 + tid * 16);      \
        gload16(Bh + (long)(n0 + srow) * GK      + ko, LL + 16384 + tid * 16);      \
        gload16(Bh + (long)(n0 + 64 + srow) * GK + ko, LL + 20480 + tid * 16);      \
        gload16(Bl + (long)(n0 + srow) * GK      + ko, LL + 24576 + tid * 16);      \
        gload16(Bl + (long)(n0 + 64 + srow) * GK + ko, LL + 28672 + tid * 16);      \
    } while (0)

    STAGE(0, 0);
    __syncthreads();                             // tile 0 landed (full drain)
#pragma unroll
    for (int kt = 0; kt < 12; ++kt) {            // GK/32 == 12
        if (kt + 1 < 12) STAGE((kt + 1) & 1, kt + 1);   // prefetch next buffer

        const char* L = smem + (kt & 1) * 32768;
        bf16x8 af[4][2], bf[4][2];
#pragma unroll
        for (int mi = 0; mi < 4; ++mi) {
            int r = wm * 64 + mi * 16 + lr;
            int off = r * 64 + (((lg ^ (r >> 1)) & 3) << 4);
            af[mi][0] = *(const bf16x8*)(L + off);
            af[mi][1] = *(const bf16x8*)(L + 8192 + off);
        }
#pragma unroll
        for (int ni = 0; ni < 4; ++ni) {
            int r = wn * 64 + ni * 16 + lr;
            int off = r * 64 + (((lg ^ (r >> 1)) & 3) << 4);
            bf[ni][0] = *(const bf16x8*)(L + 16384 + off);
            bf[ni][1] = *(const bf16x8*)(L + 24576 + off);
        }

        __builtin_amdgcn_s_setprio(1);
#pragma unroll
        for (int mi = 0; mi < 4; ++mi)
#pragma unroll
            for (int ni = 0; ni < 4; ++ni) {
                acc[mi][ni] = __builtin_amdgcn_mfma_f32_16x16x32_bf16(af[mi][0], bf[ni][0], acc[mi][ni], 0, 0, 0);
                acc[mi][ni] = __builtin_amdgcn_mfma_f32_16x16x32_bf16(af[mi][0], bf[ni][1], acc[mi][ni], 0, 0, 0);
                acc[mi][ni] = __builtin_amdgcn_mfma_f32_16x16x32_bf16(af[mi][1], bf[ni][0], acc[mi][ni], 0, 0, 0);
            }
        __builtin_amdgcn_s_setprio(0);
        __syncthreads();   // drains vmcnt (next tile in LDS) + all waves done reading cur
    }
#undef STAGE

#pragma unroll
    for (int mi = 0; mi < 4; ++mi)
#pragma unroll
        for (int ni = 0; ni < 4; ++ni) {
            int row = m0 + wm * 64 + mi * 16 + lg * 4;
            int col = n0 + wn * 64 + ni * 16 + lr;
            float* cp = C + (long)row * HW + col;
            cp[0]          = acc[mi][ni][0];
            cp[(long)HW]   = acc[mi][ni][1];
            cp[2L * HW]    = acc[mi][ni][2];
            cp[3L * HW]    = acc[mi][ni][3];
        }
}

// ---------------- transpose + split convert: [384][HW] fp32 -> [HW][384] bf16 hi/lo ----
__global__ __launch_bounds__(256)
void convT_kernel(const float* __restrict__ in, u16* __restrict__ oh, u16* __restrict__ ol,
                  long ibs, long obs)
{
    const int b = blockIdx.z;
    in += (long)b * ibs; oh += (long)b * obs; ol += (long)b * obs;
    __shared__ float t[32][33];
    const int p0 = blockIdx.x * 32, c0 = blockIdx.y * 32;
    const int ty = threadIdx.x >> 5, tx = threadIdx.x & 31;
#pragma unroll
    for (int it = 0; it < 4; ++it) {
        int c = ty + it * 8;
        t[c][tx] = in[(long)(c0 + c) * HW + p0 + tx];
    }
    __syncthreads();
    const int cp = threadIdx.x & 15;
    const int py = threadIdx.x >> 4;
#pragma unroll
    for (int half = 0; half < 2; ++half) {
        int p = py + half * 16;
        u16 h0, l0, h1, l1;
        split2(t[2 * cp][p], h0, l0);
        split2(t[2 * cp + 1][p], h1, l1);
        long o = (long)(p0 + p) * CDIM + c0 + 2 * cp;
        *(ushort2*)&oh[o] = (ushort2){h0, h1};
        *(ushort2*)&ol[o] = (ushort2){l0, l1};
    }
}

// ---------------- elementwise split convert (qkv_w) ----------------
__global__ __launch_bounds__(256)
void convA_kernel(const float* __restrict__ in, u16* __restrict__ oh, u16* __restrict__ ol, int n)
{
    int i = blockIdx.x * 256 + threadIdx.x;
    if (i < n) split2(in[i], oh[i], ol[i]);
}

// ---------------- depthwise 3x3, pad 1 — q,k channels only (0..767) ----------------
__global__ __launch_bounds__(256)
void dwconv_kernel(const float* __restrict__ in, const float* __restrict__ w,
                   float* __restrict__ out)
{
    const long base = (long)blockIdx.y * QKVC * HW;
    const int idx = blockIdx.x * 256 + threadIdx.x;      // over 768*HW/8
    const int ch = idx >> 11;
    const int wi = idx & 2047;
    const int y = wi >> 4, x0 = (wi & 15) * 8;
    const float* wp = w + ch * 9;
    const float* ip = in + base + (long)ch * HW;
    float o[8] = {0.f, 0.f, 0.f, 0.f, 0.f, 0.f, 0.f, 0.f};
#pragma unroll
    for (int dy = -1; dy <= 1; ++dy) {
        int yy = y + dy;
        if ((unsigned)yy >= 128u) continue;
        const float* rp = ip + yy * WIDTH + x0;
        float4 a  = *(const float4*)rp;
        float4 bq = *(const float4*)(rp + 4);
        float v[10] = { (x0 > 0) ? rp[-1] : 0.f,
                        a.x, a.y, a.z, a.w, bq.x, bq.y, bq.z, bq.w,
                        (x0 < 120) ? rp[8] : 0.f };
        float w0 = wp[(dy + 1) * 3], w1 = wp[(dy + 1) * 3 + 1], w2 = wp[(dy + 1) * 3 + 2];
#pragma unroll
        for (int j = 0; j < 8; ++j)
            o[j] = fmaf(w0, v[j], fmaf(w1, v[j + 1], fmaf(w2, v[j + 2], o[j])));
    }
    float* op = out + base + (long)ch * HW + y * WIDTH + x0;
    *(float4*)op       = (float4){o[0], o[1], o[2], o[3]};
    *(float4*)(op + 4) = (float4){o[4], o[5], o[6], o[7]};
}

// ---------------- depthwise 3x3 for v + fused transpose/split to vt[HW][384] ----------
__global__ __launch_bounds__(256)
void dwconv_vT_kernel(const float* __restrict__ in, const float* __restrict__ w,
                      u16* __restrict__ oh, u16* __restrict__ ol, long ibs, long obs)
{
    const int b  = blockIdx.z;
    const int cg = blockIdx.y;                   // channel group (96 ch)
    const int p0 = blockIdx.x * 64;
    const int y  = p0 >> 7, xh = p0 & 127;
    __shared__ unsigned pk[64][97];

    const int tid = threadIdx.x;
    const int seg = tid & 7;
    const int chl = tid >> 3;
    const int x0  = xh + seg * 8;
#pragma unroll
    for (int cp = 0; cp < 3; ++cp) {
        const int cl = cp * 32 + chl;
        const int c  = cg * 96 + cl;
        const float* ip = in + (long)b * ibs + (long)(768 + c) * HW;
        const float* wp = w + (768 + c) * 9;
        float o[8] = {0.f, 0.f, 0.f, 0.f, 0.f, 0.f, 0.f, 0.f};
#pragma unroll
        for (int dy = -1; dy <= 1; ++dy) {
            int yy = y + dy;
            if ((unsigned)yy >= 128u) continue;
            const float* rp = ip + yy * WIDTH + x0;
            float4 a  = *(const float4*)rp;
            float4 bq = *(const float4*)(rp + 4);
            float v[10] = { (x0 > 0) ? rp[-1] : 0.f,
                            a.x, a.y, a.z, a.w, bq.x, bq.y, bq.z, bq.w,
                            (x0 < 120) ? rp[8] : 0.f };
            float w0 = wp[(dy + 1) * 3], w1 = wp[(dy + 1) * 3 + 1], w2 = wp[(dy + 1) * 3 + 2];
#pragma unroll
            for (int j = 0; j < 8; ++j)
                o[j] = fmaf(w0, v[j], fmaf(w1, v[j + 1], fmaf(w2, v[j + 2], o[j])));
        }
#pragma unroll
        for (int j = 0; j < 8; ++j) {
            u16 hh, ll;
            split2(o[j], hh, ll);
            pk[seg * 8 + j][cl] = ((unsigned)hh << 16) | ll;
        }
    }
    __syncthreads();
    const int px = tid >> 2, qt = tid & 3;
    u16 hs[24], ls[24];
#pragma unroll
    for (int j = 0; j < 24; ++j) {
        unsigned v = pk[px][qt * 24 + j];
        hs[j] = (u16)(v >> 16);
        ls[j] = (u16)(v & 0xffffu);
    }
    u16* ph = oh + (long)b * obs + (long)(p0 + px) * CDIM + cg * 96 + qt * 24;
    u16* pl = ol + (long)b * obs + (long)(p0 + px) * CDIM + cg * 96 + qt * 24;
#pragma unroll
    for (int j = 0; j < 3; ++j) {
        *(u16x8*)(ph + j * 8) = *(const u16x8*)&hs[j * 8];
        *(u16x8*)(pl + j * 8) = *(const u16x8*)&ls[j * 8];
    }
}

// ---------------- attn partial: 48x48 dots over 512-px slice + q/k sumsq partials ----
// LDS c-major qs[48][68]: staging writes AND compute reads are float4 (b128),
// ~2x fewer LDS issue cycles than n-major b32; conflict-free (broadcast reads,
// 2-way-aliased writes). fma order n-ascending -> bitwise-identical results.
__global__ __launch_bounds__(256)
void attn_partial_kernel(const float* __restrict__ dw, float* __restrict__ part,
                         float* __restrict__ part2, long ps, long p2s)
{
    const int split = blockIdx.x, h = blockIdx.y, b = blockIdx.z;
    const int n0 = split * (HW / NSPLIT);
    const float* qbase = dw + ((long)b * QKVC + h * CH) * HW;
    const float* kbase = dw + ((long)b * QKVC + CDIM + h * CH) * HW;
    __shared__ float qs[48][68];
    __shared__ float ks[48][68];
    const int tid = threadIdx.x;
    const int tr = tid >> 4, tc = tid & 15;
    const int c0 = tr * 3, d0 = tc * 3;
    float acc[3][3] = {{0.f}};
    float qss[3] = {0.f, 0.f, 0.f}, kss[3] = {0.f, 0.f, 0.f};
    const int cA = tid >> 4;
    const int nq = (tid & 15) * 4;

#define DOT4(I, J, Q, K) do {                               \
        acc[I][J] = fmaf((Q).x, (K).x, acc[I][J]);          \
        acc[I][J] = fmaf((Q).y, (K).y, acc[I][J]);          \
        acc[I][J] = fmaf((Q).z, (K).z, acc[I][J]);          \
        acc[I][J] = fmaf((Q).w, (K).w, acc[I][J]);          \
    } while (0)

    for (int ns = 0; ns < HW / NSPLIT; ns += 64) {
        __syncthreads();
#pragma unroll
        for (int t = 0; t < 3; ++t) {
            int c = cA + t * 16;
            float4 qv = *(const float4*)(qbase + (long)c * HW + n0 + ns + nq);
            float4 kv = *(const float4*)(kbase + (long)c * HW + n0 + ns + nq);
            *(float4*)&qs[c][nq] = qv;
            *(float4*)&ks[c][nq] = kv;
            qss[t] += qv.x * qv.x + qv.y * qv.y + qv.z * qv.z + qv.w * qv.w;
            kss[t] += kv.x * kv.x + kv.y * kv.y + kv.z * kv.z + kv.w * kv.w;
        }
        __syncthreads();
#pragma unroll 4
        for (int nn = 0; nn < 64; nn += 4) {
            float4 qa = *(const float4*)&qs[c0 + 0][nn];
            float4 qb = *(const float4*)&qs[c0 + 1][nn];
            float4 qc = *(const float4*)&qs[c0 + 2][nn];
            float4 ka = *(const float4*)&ks[d0 + 0][nn];
            float4 kb = *(const float4*)&ks[d0 + 1][nn];
            float4 kc = *(const float4*)&ks[d0 + 2][nn];
            DOT4(0, 0, qa, ka); DOT4(0, 1, qa, kb); DOT4(0, 2, qa, kc);
            DOT4(1, 0, qb, ka); DOT4(1, 1, qb, kb); DOT4(1, 2, qb, kc);
            DOT4(2, 0, qc, ka); DOT4(2, 1, qc, kb); DOT4(2, 2, qc, kc);
        }
    }
#undef DOT4
#pragma unroll
    for (int m = 1; m < 16; m <<= 1) {
#pragma unroll
        for (int t = 0; t < 3; ++t) {
            qss[t] += __shfl_xor(qss[t], m);
            kss[t] += __shfl_xor(kss[t], m);
        }
    }
    if ((tid & 15) == 0) {
        float* p2 = part2 + (long)b * p2s + ((long)h * NSPLIT + split) * 96;
#pragma unroll
        for (int t = 0; t < 3; ++t) {
            p2[cA + t * 16]      = qss[t];
            p2[48 + cA + t * 16] = kss[t];
        }
    }
    float* po = part + (long)b * ps + ((long)h * NSPLIT + split) * (CH * CH);
#pragma unroll
    for (int i = 0; i < 3; ++i)
#pragma unroll
        for (int j = 0; j < 3; ++j)
            po[(c0 + i) * CH + d0 + j] = acc[i][j];
}

// ---------------- attn reduce: sum partials, inv-norms from sumsq, temperature ----
__global__ __launch_bounds__(256)
void attn_reduce_kernel(const float* __restrict__ part, const float* __restrict__ part2,
                        const float* __restrict__ temp, float* __restrict__ attn,
                        long ps, long p2s, long as_)
{
    const int seg = blockIdx.x, h = blockIdx.y, b = blockIdx.z;
    const float* pp = part + (long)b * ps + (long)h * NSPLIT * (CH * CH);
    const float* p2 = part2 + (long)b * p2s + (long)h * NSPLIT * 96;
    __shared__ float sinv[96];
    if (threadIdx.x < 96) {
        float s = 0.f;
        for (int sp = 0; sp < NSPLIT; ++sp) s += p2[sp * 96 + threadIdx.x];
        sinv[threadIdx.x] = 1.f / fmaxf(sqrtf(s), 1e-12f);
    }
    __syncthreads();
    const float t = temp[h];
    const int idx = seg * 256 + threadIdx.x;
    const int c = idx / CH, d = idx % CH;
    float s = 0.f;
    for (int sp = 0; sp < NSPLIT; ++sp) s += pp[sp * (CH * CH) + idx];
    attn[(long)b * as_ + (long)h * (CH * CH) + idx] = s * sinv[c] * sinv[48 + d] * t;
}

// ---------------- two-stage masked softmax -> combined weights W ----------------
__global__ __launch_bounds__(256)
void maskw_kernel(const float* __restrict__ attn, const float* __restrict__ attns,
                  float* __restrict__ W, long as_, long ws_)
{
    const int h = blockIdx.y, b = blockIdx.z;
    const int wave = threadIdx.x >> 6, lane = threadIdx.x & 63;
    const int r = blockIdx.x * 4 + wave;                 // 0..47
    const float* ap = attn + (long)b * as_ + (long)h * (CH * CH) + (long)r * CH;
    float a = (lane < CH) ? ap[lane] : -3.4e38f;

    int rank = 0;
#pragma unroll
    for (int j = 0; j < CH; ++j) {
        float aj = __shfl(a, j);
        rank += (aj > a) || (aj == a && j < lane);
    }
    const bool keep = (lane < CH) && (rank < 24);
    float m = keep ? a : -3.4e38f;
#pragma unroll
    for (int o = 32; o > 0; o >>= 1) m = fmaxf(m, __shfl_xor(m, o));
    float e = keep ? expf(a - m) : 0.f;
    float s = e;
#pragma unroll
    for (int o = 32; o > 0; o >>= 1) s += __shfl_xor(s, o);
    const float A1 = e / s;

    int rank2 = 0;
#pragma unroll
    for (int j = 0; j < CH; ++j) {
        float aj = __shfl(A1, j);
        rank2 += (aj > A1) || (aj == A1 && j < lane);
    }
    const bool keep2 = (lane < CH) && (rank2 < 36);
    float m2 = keep2 ? A1 : -3.4e38f;
#pragma unroll
    for (int o = 32; o > 0; o >>= 1) m2 = fmaxf(m2, __shfl_xor(m2, o));
    float e2 = keep2 ? expf(A1 - m2) : 0.f;
    float s2 = e2;
#pragma unroll
    for (int o = 32; o > 0; o >>= 1) s2 += __shfl_xor(s2, o);

    if (lane < CH)
        W[(long)b * ws_ + (long)h * (CH * CH) + (long)r * CH + lane] =
            attns[0] * A1 + attns[1] * (e2 / s2);
}

// ---------------- M = P @ blockdiag(W), written as bf16 hi/lo planes ----------------
__global__ __launch_bounds__(256)
void mbuild_kernel(const float* __restrict__ P, const float* __restrict__ W,
                   u16* __restrict__ Mh, u16* __restrict__ Ml, long ws_, long ms)
{
    const int b = blockIdx.y;
    const int idx = blockIdx.x * 256 + threadIdx.x;
    const int o = idx / CDIM, col = idx % CDIM;
    const int h = col / CH, d = col % CH;
    const float* wp = W + (long)b * ws_ + (long)h * (CH * CH) + d;
    const float* pp = P + (long)o * CDIM + h * CH;
    float s = 0.f;
#pragma unroll
    for (int c = 0; c < CH; ++c) s = fmaf(pp[c], wp[c * CH], s);
    u16 hh, ll;
    split2(s, hh, ll);
    Mh[(long)b * ms + idx] = hh;
    Ml[(long)b * ms + idx] = ll;
}

extern "C" void kernel_launch(void* const* d_in, const int* in_sizes, int n_in,
                              void* d_out, int out_size, void* d_ws, size_t ws_size,
                              hipStream_t stream)
{
    const float* x      = (const float*)d_in[0];
    const float* qkv_w  = (const float*)d_in[1];
    const float* dw_w   = (const float*)d_in[2];
    const float* proj_w = (const float*)d_in[3];
    const float* temp   = (const float*)d_in[4];
    const float* attns  = (const float*)d_in[5];
    float* out = (float*)d_out;

    const size_t perbB = (size_t)QKVC * HW * 4;
    auto need = [&](int nb) -> size_t {
        return (size_t)nb * 2 * perbB + 4u * QKVC * CDIM + 4096;
    };
    int NB = 4;
    while (NB > 1 && need(NB) > ws_size) NB >>= 1;

    const long fstride = (long)(perbB / 4);   // batch stride in floats
    const long ustride = (long)(perbB / 2);   // batch stride in u16

    const size_t PART_B  = 27u << 20;
    const size_t PART2_B = (29u << 20) + (512u << 10);
    const size_t ATT_B   = 30u << 20;
    const size_t WM_B    = 31u << 20;
    const size_t MH_B    = 32u << 20;
    const size_t ML_B    = 33u << 20;

    char* buf1 = (char*)d_ws;
    char* buf2 = buf1 + (size_t)NB * perbB;
    u16* Ah = (u16*)(buf2 + (size_t)NB * perbB);
    u16* Al = Ah + (size_t)QKVC * CDIM;

    convA_kernel<<<dim3((QKVC * CDIM + 255) / 256), 256, 0, stream>>>(qkv_w, Ah, Al, QKVC * CDIM);

    for (int b0 = 0; b0 < 4; b0 += NB) {
        const int nb = NB;
        float* pre = (float*)buf1;
        float* dwb = (float*)buf2;
        u16* xt_h = (u16*)buf2;                u16* xt_l = xt_h + (size_t)HW * CDIM;
        // vt lives in dwb's (unused) v region: channels 768..1151
        u16* vt_h = (u16*)(dwb + (size_t)768 * HW);
        u16* vt_l = vt_h + (size_t)CDIM * HW;
        float* part  = (float*)(buf1 + PART_B);
        float* part2 = (float*)(buf1 + PART2_B);
        float* attn  = (float*)(buf1 + ATT_B);
        float* Wm    = (float*)(buf1 + WM_B);
        u16* Mh = (u16*)(buf1 + MH_B);
        u16* Ml = (u16*)(buf1 + ML_B);

        // 1) x -> xt (transposed bf16 hi/lo)
        convT_kernel<<<dim3(HW / 32, CDIM / 32, nb), 256, 0, stream>>>(
            x + (size_t)b0 * CDIM * HW, xt_h, xt_l, (long)CDIM * HW, ustride);
        // 2) pre = qkv_w @ x  (MFMA split-bf16, 128x128, 2 blocks/CU)
        mfma_gemm<<<dim3(HW / 128, QKVC / 128, nb), 256, 65536, stream>>>(
            Ah, Al, xt_h, xt_l, pre, QKVC / 128, 0L, ustride, fstride);
        // 3) depthwise 3x3 for q,k (overwrites xt region with dwb)
        dwconv_kernel<<<dim3(768 * HW / 8 / 256, nb), 256, 0, stream>>>(pre, dw_w, dwb);
        // 3b) depthwise 3x3 for v fused with transpose+split -> vt
        dwconv_vT_kernel<<<dim3(HW / 64, 4, nb), 256, 0, stream>>>(pre, dw_w, vt_h, vt_l,
                                                                   fstride, ustride);
        // 4) attn partials + sumsq partials (c-major float4 LDS)
        attn_partial_kernel<<<dim3(NSPLIT, HEADS, nb), 256, 0, stream>>>(dwb, part, part2,
                                                                         fstride, fstride);
        // 5) reduce + inv-norms + scale (9-way parallel)
        attn_reduce_kernel<<<dim3(9, HEADS, nb), 256, 0, stream>>>(part, part2, temp, attn,
                                                                   fstride, fstride, fstride);
        // 6) two-stage masked softmax -> W (wave-per-row, shuffle-based)
        maskw_kernel<<<dim3(12, HEADS, nb), 256, 0, stream>>>(attn, attns, Wm, fstride, fstride);
        // 7) M = proj @ blockdiag(W) -> bf16 hi/lo
        mbuild_kernel<<<dim3(CDIM * CDIM / 256, nb), 256, 0, stream>>>(proj_w, Wm, Mh, Ml,
                                                                       fstride, ustride);
        // 8) out = M @ v (MFMA split-bf16)
        mfma_gemm<<<dim3(HW / 128, CDIM / 128, nb), 256, 65536, stream>>>(
            Mh, Ml, vt_h, vt_l, out + (size_t)b0 * CDIM * HW, CDIM / 128,
            ustride, ustride, (long)CDIM * HW);
    }
}

// Round 13
// 600.064 us; speedup vs baseline: 1.9009x; 1.0307x over previous
//
#include <hip/hip_runtime.h>
#include <math.h>

#define HW     16384
#define WIDTH  128
#define CDIM   384
#define QKVC   1152
#define HEADS  8
#define CH     48
#define NSPLIT 32
#define GK     384

typedef unsigned short u16;
typedef short bf16x8 __attribute__((ext_vector_type(8)));
typedef u16 u16x8 __attribute__((ext_vector_type(8)));
typedef float f32x4 __attribute__((ext_vector_type(4)));

#define SCHED_FENCE() __builtin_amdgcn_sched_barrier(0)

// ---- fp32 -> bf16 hi/lo split (RNE both) ----
__device__ __forceinline__ void split2(float x, u16& h, u16& l) {
    union { float f; unsigned u; } a, b, c;
    a.f = x;
    unsigned hu = (a.u + 0x7fffu + ((a.u >> 16) & 1u)) & 0xffff0000u;
    b.u = hu;
    h = (u16)(hu >> 16);
    c.f = x - b.f;
    l = (u16)((c.u + 0x7fffu + ((c.u >> 16) & 1u)) >> 16);
}

__device__ __forceinline__ void gload16(const void* g, void* l) {
    __builtin_amdgcn_global_load_lds((const __attribute__((address_space(1))) unsigned int*)g,
                                     (__attribute__((address_space(3))) unsigned int*)l, 16, 0, 0);
}

// ---------------- MFMA split-bf16 GEMM: BM=128 BN=128 BK=32, 4 waves ----------------
// 64KB LDS (2 x 32KB dbuf), 2 blocks/CU. COUNTED-vmcnt 2-deep pipeline: loads for
// tile kt+1 stay in flight across the kt barriers (vmcnt(8), never 0 mid-loop).
// RACE FIX vs r9: sched_barrier(0) on BOTH sides of every raw s_barrier —
// s_barrier is not a compiler fence, and hipcc hoisted STAGE above it (rule #19:
// co-compiled kernels perturb scheduling; r5-r8 passed by luck, r9 raced).
__global__ __launch_bounds__(256)
void mfma_gemm(const u16* __restrict__ Ah, const u16* __restrict__ Al,
               const u16* __restrict__ Bh, const u16* __restrict__ Bl,
               float* __restrict__ C, int nmb,
               long abs_, long bbs, long cbs)
{
    extern __shared__ char smem[];
    const int tot = gridDim.x * gridDim.y;
    const int per = tot >> 3;
    const int fl  = blockIdx.x + gridDim.x * blockIdx.y;
    const int f2  = (fl & 7) * per + (fl >> 3);
    const int nblk = f2 / nmb, mblk = f2 % nmb;
    const int b = blockIdx.z;
    Ah += (long)b * abs_; Al += (long)b * abs_;
    Bh += (long)b * bbs;  Bl += (long)b * bbs;
    C  += (long)b * cbs;
    const int m0 = mblk * 128, n0 = nblk * 128;

    const int tid  = threadIdx.x;
    const int wave = tid >> 6, lane = tid & 63;
    const int lr = lane & 15, lg = lane >> 4;
    const int wm = wave >> 1, wn = wave & 1;     // 2x2 wave grid, wave tile 64x64

    const int srow = tid >> 2;                   // 0..63
    const int kc   = tid & 3;
    const int sw   = kc ^ ((srow >> 1) & 3);

    f32x4 acc[4][4];
#pragma unroll
    for (int i = 0; i < 4; ++i)
#pragma unroll
        for (int j = 0; j < 4; ++j) acc[i][j] = (f32x4){0.f, 0.f, 0.f, 0.f};

#define STAGE(bs, kt) do { char* LL = smem + (bs) * 32768;                          \
        const long ko = (long)(kt) * 32 + sw * 8;                                   \
        gload16(Ah + (long)(m0 + srow) * GK      + ko, LL + tid * 16);              \
        gload16(Ah + (long)(m0 + 64 + srow) * GK + ko, LL + 4096  + tid * 16);      \
        gload16(Al + (long)(m0 + srow) * GK      + ko, LL + 8192  + tid * 16);      \
        gload16(Al + (long)(m0 + 64 + srow) * GK + ko, LL + 12288 + tid * 16);      \
        gload16(Bh + (long)(n0 + srow) * GK      + ko, LL + 16384 + tid * 16);      \
        gload16(Bh + (long)(n0 + 64 + srow) * GK + ko, LL + 20480 + tid * 16);      \
        gload16(Bl + (long)(n0 + srow) * GK      + ko, LL + 24576 + tid * 16);      \
        gload16(Bl + (long)(n0 + 64 + srow) * GK + ko, LL + 28672 + tid * 16);      \
    } while (0)

    STAGE(0, 0);                 // 8 loads in flight
    STAGE(1, 1);                 // 16 in flight
#pragma unroll
    for (int kt = 0; kt < 12; ++kt) {            // GK/32 == 12
        // barrier 1: tile kt landed for all waves. Keep tile kt+1's 8 loads in flight.
        if (kt < 11) asm volatile("s_waitcnt vmcnt(8)" ::: "memory");
        else         asm volatile("s_waitcnt vmcnt(0)" ::: "memory");
        SCHED_FENCE();
        __builtin_amdgcn_s_barrier();
        SCHED_FENCE();                           // nothing below may hoist above barrier

        const char* L = smem + (kt & 1) * 32768;
        bf16x8 af[4][2], bf[4][2];
#pragma unroll
        for (int mi = 0; mi < 4; ++mi) {
            int r = wm * 64 + mi * 16 + lr;
            int off = r * 64 + (((lg ^ (r >> 1)) & 3) << 4);
            af[mi][0] = *(const bf16x8*)(L + off);
            af[mi][1] = *(const bf16x8*)(L + 8192 + off);
        }
#pragma unroll
        for (int ni = 0; ni < 4; ++ni) {
            int r = wn * 64 + ni * 16 + lr;
            int off = r * 64 + (((lg ^ (r >> 1)) & 3) << 4);
            bf[ni][0] = *(const bf16x8*)(L + 16384 + off);
            bf[ni][1] = *(const bf16x8*)(L + 24576 + off);
        }
        // barrier 2: all waves done reading buffer kt&1 (reads drained per-wave first)
        asm volatile("s_waitcnt lgkmcnt(0)" ::: "memory");
        SCHED_FENCE();
        __builtin_amdgcn_s_barrier();
        SCHED_FENCE();                           // STAGE below may not hoist above barrier
        if (kt < 10) STAGE(kt & 1, kt + 2);      // overwrite buffer kt&1 with tile kt+2

        __builtin_amdgcn_s_setprio(1);
#pragma unroll
        for (int mi = 0; mi < 4; ++mi)
#pragma unroll
            for (int ni = 0; ni < 4; ++ni) {
                acc[mi][ni] = __builtin_amdgcn_mfma_f32_16x16x32_bf16(af[mi][0], bf[ni][0], acc[mi][ni], 0, 0, 0);
                acc[mi][ni] = __builtin_amdgcn_mfma_f32_16x16x32_bf16(af[mi][0], bf[ni][1], acc[mi][ni], 0, 0, 0);
                acc[mi][ni] = __builtin_amdgcn_mfma_f32_16x16x32_bf16(af[mi][1], bf[ni][0], acc[mi][ni], 0, 0, 0);
            }
        __builtin_amdgcn_s_setprio(0);
    }
#undef STAGE

#pragma unroll
    for (int mi = 0; mi < 4; ++mi)
#pragma unroll
        for (int ni = 0; ni < 4; ++ni) {
            int row = m0 + wm * 64 + mi * 16 + lg * 4;
            int col = n0 + wn * 64 + ni * 16 + lr;
            float* cp = C + (long)row * HW + col;
            cp[0]          = acc[mi][ni][0];
            cp[(long)HW]   = acc[mi][ni][1];
            cp[2L * HW]    = acc[mi][ni][2];
            cp[3L * HW]    = acc[mi][ni][3];
        }
}

// ---------------- transpose + split convert: [384][HW] fp32 -> [HW][384] bf16 hi/lo ----
__global__ __launch_bounds__(256)
void convT_kernel(const float* __restrict__ in, u16* __restrict__ oh, u16* __restrict__ ol,
                  long ibs, long obs)
{
    const int b = blockIdx.z;
    in += (long)b * ibs; oh += (long)b * obs; ol += (long)b * obs;
    __shared__ float t[32][33];
    const int p0 = blockIdx.x * 32, c0 = blockIdx.y * 32;
    const int ty = threadIdx.x >> 5, tx = threadIdx.x & 31;
#pragma unroll
    for (int it = 0; it < 4; ++it) {
        int c = ty + it * 8;
        t[c][tx] = in[(long)(c0 + c) * HW + p0 + tx];
    }
    __syncthreads();
    const int cp = threadIdx.x & 15;
    const int py = threadIdx.x >> 4;
#pragma unroll
    for (int half = 0; half < 2; ++half) {
        int p = py + half * 16;
        u16 h0, l0, h1, l1;
        split2(t[2 * cp][p], h0, l0);
        split2(t[2 * cp + 1][p], h1, l1);
        long o = (long)(p0 + p) * CDIM + c0 + 2 * cp;
        *(ushort2*)&oh[o] = (ushort2){h0, h1};
        *(ushort2*)&ol[o] = (ushort2){l0, l1};
    }
}

// ---------------- elementwise split convert (qkv_w) ----------------
__global__ __launch_bounds__(256)
void convA_kernel(const float* __restrict__ in, u16* __restrict__ oh, u16* __restrict__ ol, int n)
{
    int i = blockIdx.x * 256 + threadIdx.x;
    if (i < n) split2(in[i], oh[i], ol[i]);
}

// ---------------- depthwise 3x3, pad 1 — q,k channels only (0..767) ----------------
__global__ __launch_bounds__(256)
void dwconv_kernel(const float* __restrict__ in, const float* __restrict__ w,
                   float* __restrict__ out)
{
    const long base = (long)blockIdx.y * QKVC * HW;
    const int idx = blockIdx.x * 256 + threadIdx.x;      // over 768*HW/8
    const int ch = idx >> 11;
    const int wi = idx & 2047;
    const int y = wi >> 4, x0 = (wi & 15) * 8;
    const float* wp = w + ch * 9;
    const float* ip = in + base + (long)ch * HW;
    float o[8] = {0.f, 0.f, 0.f, 0.f, 0.f, 0.f, 0.f, 0.f};
#pragma unroll
    for (int dy = -1; dy <= 1; ++dy) {
        int yy = y + dy;
        if ((unsigned)yy >= 128u) continue;
        const float* rp = ip + yy * WIDTH + x0;
        float4 a  = *(const float4*)rp;
        float4 bq = *(const float4*)(rp + 4);
        float v[10] = { (x0 > 0) ? rp[-1] : 0.f,
                        a.x, a.y, a.z, a.w, bq.x, bq.y, bq.z, bq.w,
                        (x0 < 120) ? rp[8] : 0.f };
        float w0 = wp[(dy + 1) * 3], w1 = wp[(dy + 1) * 3 + 1], w2 = wp[(dy + 1) * 3 + 2];
#pragma unroll
        for (int j = 0; j < 8; ++j)
            o[j] = fmaf(w0, v[j], fmaf(w1, v[j + 1], fmaf(w2, v[j + 2], o[j])));
    }
    float* op = out + base + (long)ch * HW + y * WIDTH + x0;
    *(float4*)op       = (float4){o[0], o[1], o[2], o[3]};
    *(float4*)(op + 4) = (float4){o[4], o[5], o[6], o[7]};
}

// ---------------- depthwise 3x3 for v + fused transpose/split to vt[HW][384] ----------
__global__ __launch_bounds__(256)
void dwconv_vT_kernel(const float* __restrict__ in, const float* __restrict__ w,
                      u16* __restrict__ oh, u16* __restrict__ ol, long ibs, long obs)
{
    const int b  = blockIdx.z;
    const int cg = blockIdx.y;                   // channel group (96 ch)
    const int p0 = blockIdx.x * 64;
    const int y  = p0 >> 7, xh = p0 & 127;
    __shared__ unsigned pk[64][97];

    const int tid = threadIdx.x;
    const int seg = tid & 7;
    const int chl = tid >> 3;
    const int x0  = xh + seg * 8;
#pragma unroll
    for (int cp = 0; cp < 3; ++cp) {
        const int cl = cp * 32 + chl;
        const int c  = cg * 96 + cl;
        const float* ip = in + (long)b * ibs + (long)(768 + c) * HW;
        const float* wp = w + (768 + c) * 9;
        float o[8] = {0.f, 0.f, 0.f, 0.f, 0.f, 0.f, 0.f, 0.f};
#pragma unroll
        for (int dy = -1; dy <= 1; ++dy) {
            int yy = y + dy;
            if ((unsigned)yy >= 128u) continue;
            const float* rp = ip + yy * WIDTH + x0;
            float4 a  = *(const float4*)rp;
            float4 bq = *(const float4*)(rp + 4);
            float v[10] = { (x0 > 0) ? rp[-1] : 0.f,
                            a.x, a.y, a.z, a.w, bq.x, bq.y, bq.z, bq.w,
                            (x0 < 120) ? rp[8] : 0.f };
            float w0 = wp[(dy + 1) * 3], w1 = wp[(dy + 1) * 3 + 1], w2 = wp[(dy + 1) * 3 + 2];
#pragma unroll
            for (int j = 0; j < 8; ++j)
                o[j] = fmaf(w0, v[j], fmaf(w1, v[j + 1], fmaf(w2, v[j + 2], o[j])));
        }
#pragma unroll
        for (int j = 0; j < 8; ++j) {
            u16 hh, ll;
            split2(o[j], hh, ll);
            pk[seg * 8 + j][cl] = ((unsigned)hh << 16) | ll;
        }
    }
    __syncthreads();
    const int px = tid >> 2, qt = tid & 3;
    u16 hs[24], ls[24];
#pragma unroll
    for (int j = 0; j < 24; ++j) {
        unsigned v = pk[px][qt * 24 + j];
        hs[j] = (u16)(v >> 16);
        ls[j] = (u16)(v & 0xffffu);
    }
    u16* ph = oh + (long)b * obs + (long)(p0 + px) * CDIM + cg * 96 + qt * 24;
    u16* pl = ol + (long)b * obs + (long)(p0 + px) * CDIM + cg * 96 + qt * 24;
#pragma unroll
    for (int j = 0; j < 3; ++j) {
        *(u16x8*)(ph + j * 8) = *(const u16x8*)&hs[j * 8];
        *(u16x8*)(pl + j * 8) = *(const u16x8*)&ls[j * 8];
    }
}

// ---------------- attn partial: 48x48 dots over 512-px slice + q/k sumsq partials ----
__global__ __launch_bounds__(256)
void attn_partial_kernel(const float* __restrict__ dw, float* __restrict__ part,
                         float* __restrict__ part2, long ps, long p2s)
{
    const int split = blockIdx.x, h = blockIdx.y, b = blockIdx.z;
    const int n0 = split * (HW / NSPLIT);
    const float* qbase = dw + ((long)b * QKVC + h * CH) * HW;
    const float* kbase = dw + ((long)b * QKVC + CDIM + h * CH) * HW;
    __shared__ float qs[48][68];
    __shared__ float ks[48][68];
    const int tid = threadIdx.x;
    const int tr = tid >> 4, tc = tid & 15;
    const int c0 = tr * 3, d0 = tc * 3;
    float acc[3][3] = {{0.f}};
    float qss[3] = {0.f, 0.f, 0.f}, kss[3] = {0.f, 0.f, 0.f};
    const int cA = tid >> 4;
    const int nq = (tid & 15) * 4;

#define DOT4(I, J, Q, K) do {                               \
        acc[I][J] = fmaf((Q).x, (K).x, acc[I][J]);          \
        acc[I][J] = fmaf((Q).y, (K).y, acc[I][J]);          \
        acc[I][J] = fmaf((Q).z, (K).z, acc[I][J]);          \
        acc[I][J] = fmaf((Q).w, (K).w, acc[I][J]);          \
    } while (0)

    for (int ns = 0; ns < HW / NSPLIT; ns += 64) {
        __syncthreads();
#pragma unroll
        for (int t = 0; t < 3; ++t) {
            int c = cA + t * 16;
            float4 qv = *(const float4*)(qbase + (long)c * HW + n0 + ns + nq);
            float4 kv = *(const float4*)(kbase + (long)c * HW + n0 + ns + nq);
            *(float4*)&qs[c][nq] = qv;
            *(float4*)&ks[c][nq] = kv;
            qss[t] += qv.x * qv.x + qv.y * qv.y + qv.z * qv.z + qv.w * qv.w;
            kss[t] += kv.x * kv.x + kv.y * kv.y + kv.z * kv.z + kv.w * kv.w;
        }
        __syncthreads();
#pragma unroll 4
        for (int nn = 0; nn < 64; nn += 4) {
            float4 qa = *(const float4*)&qs[c0 + 0][nn];
            float4 qb = *(const float4*)&qs[c0 + 1][nn];
            float4 qc = *(const float4*)&qs[c0 + 2][nn];
            float4 ka = *(const float4*)&ks[d0 + 0][nn];
            float4 kb = *(const float4*)&ks[d0 + 1][nn];
            float4 kc = *(const float4*)&ks[d0 + 2][nn];
            DOT4(0, 0, qa, ka); DOT4(0, 1, qa, kb); DOT4(0, 2, qa, kc);
            DOT4(1, 0, qb, ka); DOT4(1, 1, qb, kb); DOT4(1, 2, qb, kc);
            DOT4(2, 0, qc, ka); DOT4(2, 1, qc, kb); DOT4(2, 2, qc, kc);
        }
    }
#undef DOT4
#pragma unroll
    for (int m = 1; m < 16; m <<= 1) {
#pragma unroll
        for (int t = 0; t < 3; ++t) {
            qss[t] += __shfl_xor(qss[t], m);
            kss[t] += __shfl_xor(kss[t], m);
        }
    }
    if ((tid & 15) == 0) {
        float* p2 = part2 + (long)b * p2s + ((long)h * NSPLIT + split) * 96;
#pragma unroll
        for (int t = 0; t < 3; ++t) {
            p2[cA + t * 16]      = qss[t];
            p2[48 + cA + t * 16] = kss[t];
        }
    }
    float* po = part + (long)b * ps + ((long)h * NSPLIT + split) * (CH * CH);
#pragma unroll
    for (int i = 0; i < 3; ++i)
#pragma unroll
        for (int j = 0; j < 3; ++j)
            po[(c0 + i) * CH + d0 + j] = acc[i][j];
}

// ---------------- attn reduce: sum partials, inv-norms from sumsq, temperature ----
__global__ __launch_bounds__(256)
void attn_reduce_kernel(const float* __restrict__ part, const float* __restrict__ part2,
                        const float* __restrict__ temp, float* __restrict__ attn,
                        long ps, long p2s, long as_)
{
    const int seg = blockIdx.x, h = blockIdx.y, b = blockIdx.z;
    const float* pp = part + (long)b * ps + (long)h * NSPLIT * (CH * CH);
    const float* p2 = part2 + (long)b * p2s + (long)h * NSPLIT * 96;
    __shared__ float sinv[96];
    if (threadIdx.x < 96) {
        float s = 0.f;
        for (int sp = 0; sp < NSPLIT; ++sp) s += p2[sp * 96 + threadIdx.x];
        sinv[threadIdx.x] = 1.f / fmaxf(sqrtf(s), 1e-12f);
    }
    __syncthreads();
    const float t = temp[h];
    const int idx = seg * 256 + threadIdx.x;
    const int c = idx / CH, d = idx % CH;
    float s = 0.f;
    for (int sp = 0; sp < NSPLIT; ++sp) s += pp[sp * (CH * CH) + idx];
    attn[(long)b * as_ + (long)h * (CH * CH) + idx] = s * sinv[c] * sinv[48 + d] * t;
}

// ---------------- two-stage masked softmax -> combined weights W ----------------
__global__ __launch_bounds__(256)
void maskw_kernel(const float* __restrict__ attn, const float* __restrict__ attns,
                  float* __restrict__ W, long as_, long ws_)
{
    const int h = blockIdx.y, b = blockIdx.z;
    const int wave = threadIdx.x >> 6, lane = threadIdx.x & 63;
    const int r = blockIdx.x * 4 + wave;                 // 0..47
    const float* ap = attn + (long)b * as_ + (long)h * (CH * CH) + (long)r * CH;
    float a = (lane < CH) ? ap[lane] : -3.4e38f;

    int rank = 0;
#pragma unroll
    for (int j = 0; j < CH; ++j) {
        float aj = __shfl(a, j);
        rank += (aj > a) || (aj == a && j < lane);
    }
    const bool keep = (lane < CH) && (rank < 24);
    float m = keep ? a : -3.4e38f;
#pragma unroll
    for (int o = 32; o > 0; o >>= 1) m = fmaxf(m, __shfl_xor(m, o));
    float e = keep ? expf(a - m) : 0.f;
    float s = e;
#pragma unroll
    for (int o = 32; o > 0; o >>= 1) s += __shfl_xor(s, o);
    const float A1 = e / s;

    int rank2 = 0;
#pragma unroll
    for (int j = 0; j < CH; ++j) {
        float aj = __shfl(A1, j);
        rank2 += (aj > A1) || (aj == A1 && j < lane);
    }
    const bool keep2 = (lane < CH) && (rank2 < 36);
    float m2 = keep2 ? A1 : -3.4e38f;
#pragma unroll
    for (int o = 32; o > 0; o >>= 1) m2 = fmaxf(m2, __shfl_xor(m2, o));
    float e2 = keep2 ? expf(A1 - m2) : 0.f;
    float s2 = e2;
#pragma unroll
    for (int o = 32; o > 0; o >>= 1) s2 += __shfl_xor(s2, o);

    if (lane < CH)
        W[(long)b * ws_ + (long)h * (CH * CH) + (long)r * CH + lane] =
            attns[0] * A1 + attns[1] * (e2 / s2);
}

// ---------------- M = P @ blockdiag(W), written as bf16 hi/lo planes ----------------
__global__ __launch_bounds__(256)
void mbuild_kernel(const float* __restrict__ P, const float* __restrict__ W,
                   u16* __restrict__ Mh, u16* __restrict__ Ml, long ws_, long ms)
{
    const int b = blockIdx.y;
    const int idx = blockIdx.x * 256 + threadIdx.x;
    const int o = idx / CDIM, col = idx % CDIM;
    const int h = col / CH, d = col % CH;
    const float* wp = W + (long)b * ws_ + (long)h * (CH * CH) + d;
    const float* pp = P + (long)o * CDIM + h * CH;
    float s = 0.f;
#pragma unroll
    for (int c = 0; c < CH; ++c) s = fmaf(pp[c], wp[c * CH], s);
    u16 hh, ll;
    split2(s, hh, ll);
    Mh[(long)b * ms + idx] = hh;
    Ml[(long)b * ms + idx] = ll;
}

extern "C" void kernel_launch(void* const* d_in, const int* in_sizes, int n_in,
                              void* d_out, int out_size, void* d_ws, size_t ws_size,
                              hipStream_t stream)
{
    const float* x      = (const float*)d_in[0];
    const float* qkv_w  = (const float*)d_in[1];
    const float* dw_w   = (const float*)d_in[2];
    const float* proj_w = (const float*)d_in[3];
    const float* temp   = (const float*)d_in[4];
    const float* attns  = (const float*)d_in[5];
    float* out = (float*)d_out;

    const size_t perbB = (size_t)QKVC * HW * 4;
    auto need = [&](int nb) -> size_t {
        return (size_t)nb * 2 * perbB + 4u * QKVC * CDIM + 4096;
    };
    int NB = 4;
    while (NB > 1 && need(NB) > ws_size) NB >>= 1;

    const long fstride = (long)(perbB / 4);   // batch stride in floats
    const long ustride = (long)(perbB / 2);   // batch stride in u16

    const size_t PART_B  = 27u << 20;
    const size_t PART2_B = (29u << 20) + (512u << 10);
    const size_t ATT_B   = 30u << 20;
    const size_t WM_B    = 31u << 20;
    const size_t MH_B    = 32u << 20;
    const size_t ML_B    = 33u << 20;

    char* buf1 = (char*)d_ws;
    char* buf2 = buf1 + (size_t)NB * perbB;
    u16* Ah = (u16*)(buf2 + (size_t)NB * perbB);
    u16* Al = Ah + (size_t)QKVC * CDIM;

    convA_kernel<<<dim3((QKVC * CDIM + 255) / 256), 256, 0, stream>>>(qkv_w, Ah, Al, QKVC * CDIM);

    for (int b0 = 0; b0 < 4; b0 += NB) {
        const int nb = NB;
        float* pre = (float*)buf1;
        float* dwb = (float*)buf2;
        u16* xt_h = (u16*)buf2;                u16* xt_l = xt_h + (size_t)HW * CDIM;
        // vt lives in dwb's (unused) v region: channels 768..1151
        u16* vt_h = (u16*)(dwb + (size_t)768 * HW);
        u16* vt_l = vt_h + (size_t)CDIM * HW;
        float* part  = (float*)(buf1 + PART_B);
        float* part2 = (float*)(buf1 + PART2_B);
        float* attn  = (float*)(buf1 + ATT_B);
        float* Wm    = (float*)(buf1 + WM_B);
        u16* Mh = (u16*)(buf1 + MH_B);
        u16* Ml = (u16*)(buf1 + ML_B);

        // 1) x -> xt (transposed bf16 hi/lo)
        convT_kernel<<<dim3(HW / 32, CDIM / 32, nb), 256, 0, stream>>>(
            x + (size_t)b0 * CDIM * HW, xt_h, xt_l, (long)CDIM * HW, ustride);
        // 2) pre = qkv_w @ x  (MFMA split-bf16, counted-vmcnt + hoist fences)
        mfma_gemm<<<dim3(HW / 128, QKVC / 128, nb), 256, 65536, stream>>>(
            Ah, Al, xt_h, xt_l, pre, QKVC / 128, 0L, ustride, fstride);
        // 3) depthwise 3x3 for q,k (overwrites xt region with dwb)
        dwconv_kernel<<<dim3(768 * HW / 8 / 256, nb), 256, 0, stream>>>(pre, dw_w, dwb);
        // 3b) depthwise 3x3 for v fused with transpose+split -> vt
        dwconv_vT_kernel<<<dim3(HW / 64, 4, nb), 256, 0, stream>>>(pre, dw_w, vt_h, vt_l,
                                                                   fstride, ustride);
        // 4) attn partials + sumsq partials (c-major float4 LDS)
        attn_partial_kernel<<<dim3(NSPLIT, HEADS, nb), 256, 0, stream>>>(dwb, part, part2,
                                                                         fstride, fstride);
        // 5) reduce + inv-norms + scale (9-way parallel)
        attn_reduce_kernel<<<dim3(9, HEADS, nb), 256, 0, stream>>>(part, part2, temp, attn,
                                                                   fstride, fstride, fstride);
        // 6) two-stage masked softmax -> W (wave-per-row, shuffle-based)
        maskw_kernel<<<dim3(12, HEADS, nb), 256, 0, stream>>>(attn, attns, Wm, fstride, fstride);
        // 7) M = proj @ blockdiag(W) -> bf16 hi/lo
        mbuild_kernel<<<dim3(CDIM * CDIM / 256, nb), 256, 0, stream>>>(proj_w, Wm, Mh, Ml,
                                                                       fstride, ustride);
        // 8) out = M @ v (MFMA split-bf16, counted-vmcnt + hoist fences)
        mfma_gemm<<<dim3(HW / 128, CDIM / 128, nb), 256, 65536, stream>>>(
            Mh, Ml, vt_h, vt_l, out + (size_t)b0 * CDIM * HW, CDIM / 128,
            ustride, ustride, (long)CDIM * HW);
    }
}